// Round 1
// baseline (1613.458 us; speedup 1.0000x reference)
//
#include <hip/hip_runtime.h>
#include <hip/hip_bf16.h>

// Problem: 2-layer RNN LM. V=32000, B=32, T=128, H=256.
// Inputs: tokens[B,T] i32, lengths[B] i32, emb[V,H] f32,
//         Wh0,Wx0,Wy0 [H,H], bh0,by0 [H], Wh1,Wx1,Wy1 [H,H], bh1,by1 [H]
// Outputs (concat fp32): probs[B,T,V] then h[B,T,H]  (both masked by t<len[b])

typedef _Float16 f16x8 __attribute__((ext_vector_type(8)));
typedef _Float16 f16x4 __attribute__((ext_vector_type(4)));
typedef float f32x4 __attribute__((ext_vector_type(4)));

#define NROWS 4096      // B*T
#define HDIM 256
#define VOC 32000
#define VT 128          // vocab tile in logits kernel
#define NVT 250         // VOC/VT

__device__ __forceinline__ float tanh_fast(float x) {
    float e = __expf(2.f * x);
    return 1.f - 2.f / (e + 1.f);
}

// ---------------- fp32 -> fp16 convert (emb) ----------------
__global__ __launch_bounds__(256) void cvt_kernel(const float* __restrict__ in,
                                                  _Float16* __restrict__ out, int n4) {
    int i = blockIdx.x * 256 + threadIdx.x;
    if (i < n4) {
        float4 v = ((const float4*)in)[i];
        f16x4 o = {(_Float16)v.x, (_Float16)v.y, (_Float16)v.z, (_Float16)v.w};
        ((f16x4*)out)[i] = o;
    }
}

// ---------------- Wc = Wy0 @ Wx1 ; bc = by0 @ Wx1 + bh1 ----------------
__global__ __launch_bounds__(256) void wc_kernel(const float* __restrict__ Wy0,
                                                 const float* __restrict__ Wx1,
                                                 const float* __restrict__ by0,
                                                 const float* __restrict__ bh1,
                                                 float* __restrict__ Wc,
                                                 float* __restrict__ bc) {
    __shared__ float arow[HDIM];
    int i = blockIdx.x, n = threadIdx.x;
    const float* src = (i < HDIM) ? (Wy0 + i * HDIM) : by0;
    arow[n] = src[n];
    __syncthreads();
    float acc = 0.f;
#pragma unroll 8
    for (int j = 0; j < HDIM; ++j) acc += arow[j] * Wx1[j * HDIM + n];
    if (i < HDIM) Wc[i * HDIM + n] = acc;
    else bc[n] = acc + bh1[n];
}

// ---------------- rows @ W + bias  (16 rows/block, 256 cols) ----------------
// gather mode: tokens != nullptr -> rows come from emb[tokens[row]]
// KY mode: y16 != nullptr -> also write fp16 copy + masked fp32 to outp
__global__ __launch_bounds__(256) void gemm_rows(const float* __restrict__ A,
                                                 const int* __restrict__ tokens,
                                                 const float* __restrict__ emb,
                                                 const float* __restrict__ W,
                                                 const float* __restrict__ bias,
                                                 float* __restrict__ outp,
                                                 _Float16* __restrict__ y16,
                                                 const int* __restrict__ lengths) {
    __shared__ float As[16][HDIM];
    int tid = threadIdx.x;
    int r0 = blockIdx.x * 16;
#pragma unroll
    for (int i = 0; i < 16; ++i) {
        int row = r0 + i;
        float v;
        if (tokens) v = emb[(size_t)tokens[row] * HDIM + tid];
        else        v = A[(size_t)row * HDIM + tid];
        As[i][tid] = v;
    }
    __syncthreads();
    int n = tid;
    float acc[16];
#pragma unroll
    for (int r = 0; r < 16; ++r) acc[r] = 0.f;
#pragma unroll 4
    for (int j = 0; j < HDIM; ++j) {
        float wv = W[j * HDIM + n];
#pragma unroll
        for (int r = 0; r < 16; ++r) acc[r] += As[r][j] * wv;
    }
    float bb = bias[n];
#pragma unroll
    for (int r = 0; r < 16; ++r) {
        int row = r0 + r;
        float val = acc[r] + bb;
        if (y16) {
            y16[(size_t)row * HDIM + n] = (_Float16)val;
            int b = row >> 7, t = row & 127;
            outp[(size_t)row * HDIM + n] = (t < lengths[b]) ? val : 0.f;
        } else {
            outp[(size_t)row * HDIM + n] = val;
        }
    }
}

// ---------------- sequential scan: h_t = tanh(h_{t-1} @ Wh + xw_t) ----------------
// one block per batch element; Wh register-resident (64 f32/thread, 1024 threads)
__global__ __launch_bounds__(1024, 4) void scan_kernel(const float* __restrict__ xw,
                                                       const float* __restrict__ Wh,
                                                       float* __restrict__ hseq) {
    int b = blockIdx.x;
    int tid = threadIdx.x;
    int k = tid & 255, q = tid >> 8;
    float w[64];
#pragma unroll
    for (int j = 0; j < 64; ++j) w[j] = Wh[(q * 64 + j) * HDIM + k];
    __shared__ float hbuf[2][HDIM];
    __shared__ float psum[4][HDIM];
    if (tid < HDIM) hbuf[0][tid] = 0.f;
    __syncthreads();
    const float* xwb = xw + (size_t)b * 128 * HDIM;
    float* hb = hseq + (size_t)b * 128 * HDIM;
    for (int t = 0; t < 128; ++t) {
        int cur = t & 1;
        float xwv = 0.f;
        if (tid < HDIM) xwv = xwb[t * HDIM + tid];  // prefetch before FMA work
        const float4* h4 = (const float4*)(&hbuf[cur][q * 64]);
        float acc = 0.f;
#pragma unroll
        for (int jj = 0; jj < 16; ++jj) {
            float4 hv = h4[jj];
            acc += w[jj * 4 + 0] * hv.x + w[jj * 4 + 1] * hv.y +
                   w[jj * 4 + 2] * hv.z + w[jj * 4 + 3] * hv.w;
        }
        psum[q][k] = acc;
        __syncthreads();
        if (tid < HDIM) {
            float s = psum[0][tid] + psum[1][tid] + psum[2][tid] + psum[3][tid] + xwv;
            float hn = tanh_fast(s);
            hbuf[1 - cur][tid] = hn;
            hb[t * HDIM + tid] = hn;
        }
        __syncthreads();
    }
}

// ---------------- logits GEMM (fp16 MFMA) + exp + partial row sums ----------------
// grid (rt=256 fast, vt=250); tile 16 rows x 128 vocab; block 256 thr = 4 waves
__global__ __launch_bounds__(256) void logits_kernel(const _Float16* __restrict__ y16,
                                                     const _Float16* __restrict__ emb16,
                                                     const int* __restrict__ lengths,
                                                     float* __restrict__ probs,
                                                     float* __restrict__ partials) {
    int rt = blockIdx.x, vt = blockIdx.y;
    int r0 = rt * 16, v0 = vt * VT;
    int b = r0 >> 7, t0 = r0 & 127;
    int len = lengths[b];
    int tid = threadIdx.x, lane = tid & 63, wv = tid >> 6;

    if (len <= t0) {  // fully masked tile: explicit zeros (d_out is poisoned)
        float4 z = {0.f, 0.f, 0.f, 0.f};
#pragma unroll
        for (int i = 0; i < 2; ++i) {
            int fid = tid + i * 256;           // 512 float4 = 16x128 f32
            int rl = fid >> 5, c4 = fid & 31;
            ((float4*)(probs + (size_t)(r0 + rl) * VOC + v0))[c4] = z;
        }
        return;
    }

    f32x4 acc0 = {0.f, 0.f, 0.f, 0.f}, acc1 = {0.f, 0.f, 0.f, 0.f};
    int l15 = lane & 15, quad = lane >> 4;
    int kq = quad * 8;
    const f16x8* Ap = (const f16x8*)(y16 + (size_t)(r0 + l15) * HDIM + kq);
    int n0 = v0 + wv * 32;
    const f16x8* B0 = (const f16x8*)(emb16 + (size_t)(n0 + l15) * HDIM + kq);
    const f16x8* B1 = (const f16x8*)(emb16 + (size_t)(n0 + 16 + l15) * HDIM + kq);
#pragma unroll
    for (int kk = 0; kk < 8; ++kk) {   // K = 256 = 8 x 32
        f16x8 af = Ap[kk * 4];         // kk*32 halfs = kk*4 f16x8
        f16x8 b0 = B0[kk * 4];
        f16x8 b1 = B1[kk * 4];
        acc0 = __builtin_amdgcn_mfma_f32_16x16x32_f16(af, b0, acc0, 0, 0, 0);
        acc1 = __builtin_amdgcn_mfma_f32_16x16x32_f16(af, b1, acc1, 0, 0, 0);
    }

    // epilogue: exp, mask, store, per-row partial sums
    __shared__ float wsum[4][16];
    float rs[4];
#pragma unroll
    for (int r = 0; r < 4; ++r) {
        int rl = quad * 4 + r;               // C/D: col=lane&15, row=quad*4+reg
        bool ok = (t0 + rl) < len;
        float e0 = ok ? __expf(acc0[r]) : 0.f;
        float e1 = ok ? __expf(acc1[r]) : 0.f;
        size_t base = (size_t)(r0 + rl) * VOC;
        probs[base + n0 + l15] = e0;
        probs[base + n0 + 16 + l15] = e1;
        rs[r] = e0 + e1;
    }
#pragma unroll
    for (int m = 1; m < 16; m <<= 1) {
#pragma unroll
        for (int r = 0; r < 4; ++r) rs[r] += __shfl_xor(rs[r], m, 64);
    }
    if (l15 == 0) {
#pragma unroll
        for (int r = 0; r < 4; ++r) wsum[wv][quad * 4 + r] = rs[r];
    }
    __syncthreads();
    if (tid < 16) {
        float s = wsum[0][tid] + wsum[1][tid] + wsum[2][tid] + wsum[3][tid];
        partials[(size_t)(r0 + tid) * 256 + vt] = s;
    }
}

// ---------------- rescale: probs *= 1/rowsum (unmasked rows only) ----------------
__global__ __launch_bounds__(256) void rescale_kernel(float* __restrict__ probs,
                                                      const float* __restrict__ partials,
                                                      const int* __restrict__ lengths) {
    int row = blockIdx.x;
    int b = row >> 7, t = row & 127;
    if (t >= lengths[b]) return;  // masked rows already zeroed by logits_kernel
    int tid = threadIdx.x;
    float v = (tid < NVT) ? partials[(size_t)row * 256 + tid] : 0.f;
#pragma unroll
    for (int m = 32; m >= 1; m >>= 1) v += __shfl_xor(v, m, 64);
    __shared__ float wsh[4];
    __shared__ float tot;
    if ((tid & 63) == 0) wsh[tid >> 6] = v;
    __syncthreads();
    if (tid == 0) tot = 1.f / (wsh[0] + wsh[1] + wsh[2] + wsh[3]);
    __syncthreads();
    float inv = tot;
    float* rowp = probs + (size_t)row * VOC;
#pragma unroll 5
    for (int i = 0; i < 125; ++i) rowp[i * 256 + tid] *= inv;
}

extern "C" void kernel_launch(void* const* d_in, const int* in_sizes, int n_in,
                              void* d_out, int out_size, void* d_ws, size_t ws_size,
                              hipStream_t stream) {
    const int*   tokens  = (const int*)d_in[0];
    const int*   lengths = (const int*)d_in[1];
    const float* emb     = (const float*)d_in[2];
    const float* Wh0     = (const float*)d_in[3];
    const float* Wx0     = (const float*)d_in[4];
    const float* Wy0     = (const float*)d_in[5];
    const float* bh0     = (const float*)d_in[6];
    // by0 = d_in[7]
    const float* Wh1     = (const float*)d_in[8];
    const float* Wx1     = (const float*)d_in[9];
    const float* Wy1     = (const float*)d_in[10];
    const float* bh1     = (const float*)d_in[11];
    const float* by1     = (const float*)d_in[12];
    const float* by0     = (const float*)d_in[7];

    float* probs = (float*)d_out;
    float* hout  = probs + (size_t)NROWS * VOC;  // 131,072,000

    char* ws = (char*)d_ws;
    const size_t SZ_ROWS = (size_t)NROWS * HDIM * 4;   // 4 MB
    float*     xw0     = (float*)(ws);
    float*     h0seq   = (float*)(ws + SZ_ROWS);
    float*     xw1     = (float*)(ws + 2 * SZ_ROWS);
    float*     h1seq   = (float*)(ws + 3 * SZ_ROWS);
    _Float16*  y16     = (_Float16*)(ws + 4 * SZ_ROWS);
    _Float16*  emb16   = (_Float16*)(ws + 4 * SZ_ROWS + (size_t)NROWS * HDIM * 2);
    char*      after   = ws + 4 * SZ_ROWS + (size_t)NROWS * HDIM * 2 + (size_t)VOC * HDIM * 2;
    float*     Wc      = (float*)after;
    float*     bcv     = Wc + HDIM * HDIM;
    float*     partials = (float*)(after + (HDIM * HDIM + HDIM) * 4 + 1024);  // [4096][256(pad)]

    cvt_kernel<<<8000, 256, 0, stream>>>(emb, emb16, (VOC * HDIM) / 4);
    wc_kernel<<<257, 256, 0, stream>>>(Wy0, Wx1, by0, bh1, Wc, bcv);
    gemm_rows<<<NROWS / 16, 256, 0, stream>>>(nullptr, tokens, emb, Wx0, bh0, xw0, nullptr, nullptr);
    scan_kernel<<<32, 1024, 0, stream>>>(xw0, Wh0, h0seq);
    gemm_rows<<<NROWS / 16, 256, 0, stream>>>(h0seq, nullptr, nullptr, Wc, bcv, xw1, nullptr, nullptr);
    scan_kernel<<<32, 1024, 0, stream>>>(xw1, Wh1, h1seq);
    gemm_rows<<<NROWS / 16, 256, 0, stream>>>(h1seq, nullptr, nullptr, Wy1, by1, hout, y16, lengths);
    logits_kernel<<<dim3(NROWS / 16, NVT), 256, 0, stream>>>(y16, emb16, lengths, probs, partials);
    rescale_kernel<<<NROWS, 256, 0, stream>>>(probs, partials, lengths);
}

// Round 2
// 1436.993 us; speedup vs baseline: 1.1228x; 1.1228x over previous
//
#include <hip/hip_runtime.h>
#include <hip/hip_bf16.h>

// Problem: 2-layer RNN LM. V=32000, B=32, T=128, H=256.
// Outputs (concat fp32): probs[B,T,V] then h[B,T,H]  (both masked by t<len[b])

typedef _Float16 f16x8 __attribute__((ext_vector_type(8)));
typedef _Float16 f16x4 __attribute__((ext_vector_type(4)));
typedef float f32x4 __attribute__((ext_vector_type(4)));

#define NROWS 4096      // B*T
#define HDIM 256
#define VOC 32000
#define NVT2 125        // VOC / 256

__device__ __forceinline__ float tanh_fast(float x) {
    float e = __expf(2.f * x);
    return 1.f - 2.f / (e + 1.f);
}

// ---------------- fp32 -> fp16 convert (emb) ----------------
__global__ __launch_bounds__(256) void cvt_kernel(const float* __restrict__ in,
                                                  _Float16* __restrict__ out, int n4) {
    int i = blockIdx.x * 256 + threadIdx.x;
    if (i < n4) {
        float4 v = ((const float4*)in)[i];
        f16x4 o = {(_Float16)v.x, (_Float16)v.y, (_Float16)v.z, (_Float16)v.w};
        ((f16x4*)out)[i] = o;
    }
}

// ---------------- Wc = Wy0 @ Wx1 ; bc = by0 @ Wx1 + bh1 ----------------
__global__ __launch_bounds__(256) void wc_kernel(const float* __restrict__ Wy0,
                                                 const float* __restrict__ Wx1,
                                                 const float* __restrict__ by0,
                                                 const float* __restrict__ bh1,
                                                 float* __restrict__ Wc,
                                                 float* __restrict__ bc) {
    __shared__ float arow[HDIM];
    int i = blockIdx.x, n = threadIdx.x;
    const float* src = (i < HDIM) ? (Wy0 + i * HDIM) : by0;
    arow[n] = src[n];
    __syncthreads();
    float acc = 0.f;
#pragma unroll 8
    for (int j = 0; j < HDIM; ++j) acc += arow[j] * Wx1[j * HDIM + n];
    if (i < HDIM) Wc[i * HDIM + n] = acc;
    else bc[n] = acc + bh1[n];
}

// ---------------- rows @ W + bias  (16 rows/block, 256 cols) ----------------
__global__ __launch_bounds__(256) void gemm_rows(const float* __restrict__ A,
                                                 const int* __restrict__ tokens,
                                                 const float* __restrict__ emb,
                                                 const float* __restrict__ W,
                                                 const float* __restrict__ bias,
                                                 float* __restrict__ outp,
                                                 _Float16* __restrict__ y16,
                                                 const int* __restrict__ lengths) {
    __shared__ float As[16][HDIM];
    int tid = threadIdx.x;
    int r0 = blockIdx.x * 16;
#pragma unroll
    for (int i = 0; i < 16; ++i) {
        int row = r0 + i;
        float v;
        if (tokens) v = emb[(size_t)tokens[row] * HDIM + tid];
        else        v = A[(size_t)row * HDIM + tid];
        As[i][tid] = v;
    }
    __syncthreads();
    int n = tid;
    float acc[16];
#pragma unroll
    for (int r = 0; r < 16; ++r) acc[r] = 0.f;
#pragma unroll 4
    for (int j = 0; j < HDIM; ++j) {
        float wv = W[j * HDIM + n];
#pragma unroll
        for (int r = 0; r < 16; ++r) acc[r] += As[r][j] * wv;
    }
    float bb = bias[n];
#pragma unroll
    for (int r = 0; r < 16; ++r) {
        int row = r0 + r;
        float val = acc[r] + bb;
        if (y16) {
            y16[(size_t)row * HDIM + n] = (_Float16)val;
            int b = row >> 7, t = row & 127;
            outp[(size_t)row * HDIM + n] = (t < lengths[b]) ? val : 0.f;
        } else {
            outp[(size_t)row * HDIM + n] = val;
        }
    }
}

// ---------------- sequential scan: h_t = tanh(h_{t-1} @ Wh + xw_t) ----------------
__global__ __launch_bounds__(1024, 4) void scan_kernel(const float* __restrict__ xw,
                                                       const float* __restrict__ Wh,
                                                       float* __restrict__ hseq) {
    int b = blockIdx.x;
    int tid = threadIdx.x;
    int k = tid & 255, q = tid >> 8;
    float w[64];
#pragma unroll
    for (int j = 0; j < 64; ++j) w[j] = Wh[(q * 64 + j) * HDIM + k];
    __shared__ float hbuf[2][HDIM];
    __shared__ float psum[4][HDIM];
    if (tid < HDIM) hbuf[0][tid] = 0.f;
    __syncthreads();
    const float* xwb = xw + (size_t)b * 128 * HDIM;
    float* hb = hseq + (size_t)b * 128 * HDIM;
    for (int t = 0; t < 128; ++t) {
        int cur = t & 1;
        float xwv = 0.f;
        if (tid < HDIM) xwv = xwb[t * HDIM + tid];
        const float4* h4 = (const float4*)(&hbuf[cur][q * 64]);
        float acc = 0.f;
#pragma unroll
        for (int jj = 0; jj < 16; ++jj) {
            float4 hv = h4[jj];
            acc += w[jj * 4 + 0] * hv.x + w[jj * 4 + 1] * hv.y +
                   w[jj * 4 + 2] * hv.z + w[jj * 4 + 3] * hv.w;
        }
        psum[q][k] = acc;
        __syncthreads();
        if (tid < HDIM) {
            float s = psum[0][tid] + psum[1][tid] + psum[2][tid] + psum[3][tid] + xwv;
            float hn = tanh_fast(s);
            hbuf[1 - cur][tid] = hn;
            hb[t * HDIM + tid] = hn;
        }
        __syncthreads();
    }
}

// ---------------- softmax GEMM: 64 rows x 256 vocab per block, 4 waves ----------------
// wave w: rows rw = r0+(w&1)*32 (+m*16), cols nb = v0+(w>>1)*128 (8 tiles of 16)
// PHASE WRITE=false: per-row sum of exp(logit) -> partials[row][vt]
// PHASE WRITE=true : probs[row][col] = exp(logit) * inv[row]  (masked rows -> 0)
template <bool WRITE>
__global__ __launch_bounds__(256) void softmax_gemm(const _Float16* __restrict__ y16,
                                                    const _Float16* __restrict__ emb16,
                                                    const int* __restrict__ lengths,
                                                    float* __restrict__ probs,
                                                    float* __restrict__ partials,
                                                    const float* __restrict__ inv) {
    int rt = blockIdx.x, vt = blockIdx.y;
    int r0 = rt * 64, v0 = vt * 256;
    int b = r0 >> 7, t0 = r0 & 127;
    int len = lengths[b];
    int tid = threadIdx.x;

    if (len <= t0) {            // fully masked tile
        if (WRITE) {            // explicit zeros, fully coalesced float4
            float4 z = {0.f, 0.f, 0.f, 0.f};
#pragma unroll
            for (int i = 0; i < 16; ++i) {
                int fid = tid + i * 256;
                int rl = fid >> 6, c4 = fid & 63;
                ((float4*)(probs + (size_t)(r0 + rl) * VOC + v0))[c4] = z;
            }
        }
        return;
    }

    int lane = tid & 63, w = tid >> 6;
    int l15 = lane & 15, quad = lane >> 4;
    int rw = r0 + (w & 1) * 32;
    int nb = v0 + (w >> 1) * 128;
    const f16x8* Ap = (const f16x8*)(y16 + (size_t)(rw + l15) * HDIM + quad * 8);
    const f16x8* Bp = (const f16x8*)(emb16 + (size_t)(nb + l15) * HDIM + quad * 8);

    f32x4 acc[2][8];
#pragma unroll
    for (int m = 0; m < 2; ++m)
#pragma unroll
        for (int i = 0; i < 8; ++i) acc[m][i] = (f32x4){0.f, 0.f, 0.f, 0.f};

#pragma unroll
    for (int kk = 0; kk < 8; ++kk) {      // K = 256 = 8 x 32; row stride = 512 f16x8
        f16x8 a0 = Ap[kk * 4];
        f16x8 a1 = Ap[512 + kk * 4];
#pragma unroll
        for (int i = 0; i < 8; ++i) {
            f16x8 bf = Bp[i * 512 + kk * 4];
            acc[0][i] = __builtin_amdgcn_mfma_f32_16x16x32_f16(a0, bf, acc[0][i], 0, 0, 0);
            acc[1][i] = __builtin_amdgcn_mfma_f32_16x16x32_f16(a1, bf, acc[1][i], 0, 0, 0);
        }
    }

    if (!WRITE) {
        // per-row partial sums of exp over this block's 256 cols
        float rsum[2][4];
#pragma unroll
        for (int m = 0; m < 2; ++m)
#pragma unroll
            for (int r = 0; r < 4; ++r) {
                float s = 0.f;
#pragma unroll
                for (int i = 0; i < 8; ++i) s += __expf(acc[m][i][r]);
                rsum[m][r] = s;
            }
#pragma unroll
        for (int d = 1; d < 16; d <<= 1)
#pragma unroll
            for (int m = 0; m < 2; ++m)
#pragma unroll
                for (int r = 0; r < 4; ++r)
                    rsum[m][r] += __shfl_xor(rsum[m][r], d, 64);
        __shared__ float ps[2][64];
        if (l15 == 0) {
#pragma unroll
            for (int m = 0; m < 2; ++m)
#pragma unroll
                for (int r = 0; r < 4; ++r)
                    ps[w >> 1][(w & 1) * 32 + m * 16 + quad * 4 + r] = rsum[m][r];
        }
        __syncthreads();
        if (tid < 64)
            partials[(size_t)(r0 + tid) * 128 + vt] = ps[0][tid] + ps[1][tid];
    } else {
        float invv[2][4];
#pragma unroll
        for (int m = 0; m < 2; ++m)
#pragma unroll
            for (int r = 0; r < 4; ++r)
                invv[m][r] = inv[rw + m * 16 + quad * 4 + r];
#pragma unroll
        for (int m = 0; m < 2; ++m) {
#pragma unroll
            for (int r = 0; r < 4; ++r) {
                int row = rw + m * 16 + quad * 4 + r;
                bool ok = (row & 127) < len;
                float iv = invv[m][r];
                size_t base = (size_t)row * VOC + nb + l15;
#pragma unroll
                for (int i = 0; i < 8; ++i) {
                    float val = ok ? __expf(acc[m][i][r]) * iv : 0.f;
                    probs[base + i * 16] = val;
                }
            }
        }
    }
}

// ---------------- rowsum reduce: inv[row] = 1 / sum(partials[row][0..124]) ----------------
__global__ __launch_bounds__(128) void reduce_kernel(const float* __restrict__ partials,
                                                     float* __restrict__ inv) {
    int row = blockIdx.x, tid = threadIdx.x;
    float v = (tid < NVT2) ? partials[(size_t)row * 128 + tid] : 0.f;
#pragma unroll
    for (int d = 1; d < 64; d <<= 1) v += __shfl_xor(v, d, 64);
    __shared__ float s2[2];
    if ((tid & 63) == 0) s2[tid >> 6] = v;
    __syncthreads();
    if (tid == 0) inv[row] = 1.f / (s2[0] + s2[1]);
}

extern "C" void kernel_launch(void* const* d_in, const int* in_sizes, int n_in,
                              void* d_out, int out_size, void* d_ws, size_t ws_size,
                              hipStream_t stream) {
    const int*   tokens  = (const int*)d_in[0];
    const int*   lengths = (const int*)d_in[1];
    const float* emb     = (const float*)d_in[2];
    const float* Wh0     = (const float*)d_in[3];
    const float* Wx0     = (const float*)d_in[4];
    const float* Wy0     = (const float*)d_in[5];
    const float* bh0     = (const float*)d_in[6];
    const float* by0     = (const float*)d_in[7];
    const float* Wh1     = (const float*)d_in[8];
    const float* Wx1     = (const float*)d_in[9];
    const float* Wy1     = (const float*)d_in[10];
    const float* bh1     = (const float*)d_in[11];
    const float* by1     = (const float*)d_in[12];

    float* probs = (float*)d_out;
    float* hout  = probs + (size_t)NROWS * VOC;

    char* ws = (char*)d_ws;
    const size_t SZ_ROWS = (size_t)NROWS * HDIM * 4;   // 4 MB
    float*     xw0     = (float*)(ws);
    float*     h0seq   = (float*)(ws + SZ_ROWS);
    float*     xw1     = (float*)(ws + 2 * SZ_ROWS);
    float*     h1seq   = (float*)(ws + 3 * SZ_ROWS);
    _Float16*  y16     = (_Float16*)(ws + 4 * SZ_ROWS);
    _Float16*  emb16   = (_Float16*)(ws + 4 * SZ_ROWS + (size_t)NROWS * HDIM * 2);
    char*      after   = ws + 4 * SZ_ROWS + (size_t)NROWS * HDIM * 2 + (size_t)VOC * HDIM * 2;
    float*     Wc      = (float*)after;
    float*     bcv     = Wc + HDIM * HDIM;
    float*     partials = (float*)(after + (HDIM * HDIM + HDIM) * 4 + 1024);  // [4096][128]
    float*     invp    = partials + (size_t)NROWS * 128;

    cvt_kernel<<<8000, 256, 0, stream>>>(emb, emb16, (VOC * HDIM) / 4);
    wc_kernel<<<257, 256, 0, stream>>>(Wy0, Wx1, by0, bh1, Wc, bcv);
    gemm_rows<<<NROWS / 16, 256, 0, stream>>>(nullptr, tokens, emb, Wx0, bh0, xw0, nullptr, nullptr);
    scan_kernel<<<32, 1024, 0, stream>>>(xw0, Wh0, h0seq);
    gemm_rows<<<NROWS / 16, 256, 0, stream>>>(h0seq, nullptr, nullptr, Wc, bcv, xw1, nullptr, nullptr);
    scan_kernel<<<32, 1024, 0, stream>>>(xw1, Wh1, h1seq);
    gemm_rows<<<NROWS / 16, 256, 0, stream>>>(h1seq, nullptr, nullptr, Wy1, by1, hout, y16, lengths);
    softmax_gemm<false><<<dim3(64, NVT2), 256, 0, stream>>>(y16, emb16, lengths, nullptr, partials, nullptr);
    reduce_kernel<<<NROWS, 128, 0, stream>>>(partials, invp);
    softmax_gemm<true><<<dim3(64, NVT2), 256, 0, stream>>>(y16, emb16, lengths, probs, nullptr, invp);
}